// Round 6
// baseline (114.413 us; speedup 1.0000x reference)
//
#include <hip/hip_runtime.h>

using f32x4  = __attribute__((ext_vector_type(4))) float;
using bf16x8 = __attribute__((ext_vector_type(8))) short;

// Device-global handoff sim -> stream; rewritten every call before use.
__device__ __attribute__((aligned(16))) unsigned short g_P[128 * 64]; // bf16 [ReU+;ImU+;ReU-;ImU-]
__device__ float g_A00;

__device__ inline unsigned short f2bf(float x) { // fp32 -> bf16 RNE
  unsigned u = __builtin_bit_cast(unsigned, x);
  return (unsigned short)((u + 0x7FFFu + ((u >> 16) & 1u)) >> 16);
}
__device__ inline float2 cmul(float2 x, float2 y) {
  return make_float2(x.x * y.x - x.y * y.y, x.x * y.y + x.y * y.x);
}
__device__ inline float2 cfma(float2 x, float2 y, float2 a) { // a + x*y
  return make_float2(fmaf(x.x, y.x, fmaf(-x.y, y.y, a.x)),
                     fmaf(x.x, y.y, fmaf(x.y, y.x, a.y)));
}

struct u2 { float2 a, b, c, d; };  // 2x2 complex [[a,b],[c,d]]
struct c4 { float2 m[4][4]; };     // 4x4 complex; constant-indexed only (rule #20)

__device__ inline u2 mk3(const float* tS, const float* tC,
                         const float* tSh, const float* tCh, int i) {
  float ch = tCh[i], sh = tSh[i];
  float cp = tC[i + 1], sp = tS[i + 1];
  float cl = tC[i + 2], sl = tS[i + 2];
  u2 r;
  r.a = make_float2(ch, 0.f);
  r.b = make_float2(-cl * sh, -sl * sh);
  r.c = make_float2(cp * sh, sp * sh);
  r.d = make_float2((cp * cl - sp * sl) * ch, (cp * sl + sp * cl) * ch);
  return r;
}
__device__ inline c4 kron2(const u2& A, const u2& B) { // A on high bit (qa)
  c4 r;
  r.m[0][0]=cmul(A.a,B.a); r.m[0][1]=cmul(A.a,B.b); r.m[0][2]=cmul(A.b,B.a); r.m[0][3]=cmul(A.b,B.b);
  r.m[1][0]=cmul(A.a,B.c); r.m[1][1]=cmul(A.a,B.d); r.m[1][2]=cmul(A.b,B.c); r.m[1][3]=cmul(A.b,B.d);
  r.m[2][0]=cmul(A.c,B.a); r.m[2][1]=cmul(A.c,B.b); r.m[2][2]=cmul(A.d,B.a); r.m[2][3]=cmul(A.d,B.b);
  r.m[3][0]=cmul(A.c,B.c); r.m[3][1]=cmul(A.c,B.d); r.m[3][2]=cmul(A.d,B.c); r.m[3][3]=cmul(A.d,B.d);
  return r;
}
__device__ inline c4 mul4(const c4& X, const c4& Y) { // X*Y (X applied after Y)
  c4 r;
#pragma unroll
  for (int i = 0; i < 4; ++i)
#pragma unroll
    for (int j = 0; j < 4; ++j) {
      float2 s = make_float2(0.f, 0.f);
#pragma unroll
      for (int k = 0; k < 4; ++k) s = cfma(X.m[i][k], Y.m[k][j], s);
      r.m[i][j] = s;
    }
  return r;
}
__device__ inline c4 cu4(const u2& U) { // controlled-U, control = high bit
  c4 r;
#pragma unroll
  for (int i = 0; i < 4; ++i)
#pragma unroll
    for (int j = 0; j < 4; ++j) r.m[i][j] = make_float2(0.f, 0.f);
  r.m[0][0] = r.m[1][1] = make_float2(1.f, 0.f);
  r.m[2][2] = U.a; r.m[2][3] = U.b; r.m[3][2] = U.c; r.m[3][3] = U.d;
  return r;
}
__device__ inline c4 gcxp(float2 e) { // P(lam on target=low) * CX(ctrl=high)
  c4 r;
#pragma unroll
  for (int i = 0; i < 4; ++i)
#pragma unroll
    for (int j = 0; j < 4; ++j) r.m[i][j] = make_float2(0.f, 0.f);
  r.m[0][0] = make_float2(1.f, 0.f); r.m[1][1] = e;
  r.m[2][3] = make_float2(1.f, 0.f); r.m[3][2] = e;
  return r;
}

// general 4x4 on (qa=high, qb=low); psi[i*64+t], 16 quads split over sub=0..3
__device__ inline void g2q(float2* psi, int t, int sub, int qa, int qb, const c4& G) {
  const int lo = qa < qb ? qa : qb, hi = qa < qb ? qb : qa;
  const int mlo = (1 << lo) - 1, mhi = (1 << hi) - 1;
  const int dA = (1 << qa) * 64, dB = (1 << qb) * 64;
#pragma unroll
  for (int pp = 0; pp < 4; ++pp) {
    int p = sub * 4 + pp;
    int y = ((p & ~mlo) << 1) | (p & mlo);
    y     = ((y & ~mhi) << 1) | (y & mhi);
    int ad = y * 64 + t;
    float2 a0 = psi[ad], a1 = psi[ad + dB], a2 = psi[ad + dA], a3 = psi[ad + dA + dB];
    float2 o0 = cfma(G.m[0][3], a3, cfma(G.m[0][2], a2, cfma(G.m[0][1], a1, cmul(G.m[0][0], a0))));
    float2 o1 = cfma(G.m[1][3], a3, cfma(G.m[1][2], a2, cfma(G.m[1][1], a1, cmul(G.m[1][0], a0))));
    float2 o2 = cfma(G.m[2][3], a3, cfma(G.m[2][2], a2, cfma(G.m[2][1], a1, cmul(G.m[2][0], a0))));
    float2 o3 = cfma(G.m[3][3], a3, cfma(G.m[3][2], a2, cfma(G.m[3][1], a1, cmul(G.m[3][0], a0))));
    psi[ad] = o0; psi[ad + dB] = o1; psi[ad + dA] = o2; psi[ad + dA + dB] = o3;
  }
}
__device__ inline float2 pick(const u2& U, int bi, int bt) {
  return bi ? (bt ? U.d : U.c) : (bt ? U.b : U.a);
}

// ---- sim: 1 block. 7 LDS stages: layer1 = direct tensor product;
// remaining gates composed in-register into six 4x4s on qubit pairs. ----
__global__ __launch_bounds__(256) void sim_kernel(const float* __restrict__ Pp) {
  __shared__ float2 psi[64 * 64];
  __shared__ float tS[54], tC[54], tSh[54], tCh[54];
  const int tid = threadIdx.x, t = tid & 63, sub = tid >> 6;
  if (tid < 54) {
    float p = Pp[tid];
    tS[tid] = __sinf(p);  tC[tid] = __cosf(p);
    tSh[tid] = __sinf(0.5f * p); tCh[tid] = __cosf(0.5f * p);
  }
  __syncthreads();

  // stage 1: psi[i][t] = prod_q Uq[i_q][t_q]  (input = identity columns)
  {
    u2 L0 = mk3(tS, tC, tSh, tCh, 0),  L1 = mk3(tS, tC, tSh, tCh, 3);
    u2 L2 = mk3(tS, tC, tSh, tCh, 6),  L3 = mk3(tS, tC, tSh, tCh, 9);
    u2 L4 = mk3(tS, tC, tSh, tCh, 12), L5 = mk3(tS, tC, tSh, tCh, 15);
#pragma unroll
    for (int e = 0; e < 16; ++e) {
      int idx = tid + 256 * e;        // idx = i*64 + tt
      int i = idx >> 6, tt = idx & 63;
      float2 f = pick(L0, i & 1, tt & 1);
      f = cmul(f, pick(L1, (i >> 1) & 1, (tt >> 1) & 1));
      f = cmul(f, pick(L2, (i >> 2) & 1, (tt >> 2) & 1));
      f = cmul(f, pick(L3, (i >> 3) & 1, (tt >> 3) & 1));
      f = cmul(f, pick(L4, (i >> 4) & 1, (tt >> 4) & 1));
      f = cmul(f, pick(L5, (i >> 5) & 1, (tt >> 5) & 1));
      psi[idx] = f;
    }
  }
  __syncthreads();
  auto E = [&](int i) { return make_float2(tC[i], tS[i]); };
  { c4 G = gcxp(E(18)); g2q(psi, t, sub, 2, 1, G); } __syncthreads();  // CX(2,1);P18(1)
  { c4 G = gcxp(E(19)); g2q(psi, t, sub, 4, 3, G); } __syncthreads();  // CX(4,3);P19(3)
  { c4 G = mul4(cu4(mk3(tS, tC, tSh, tCh, 32)),                        // U20(0),U23(1);CU32(0->1)
                kron2(mk3(tS, tC, tSh, tCh, 20), mk3(tS, tC, tSh, tCh, 23)));
    g2q(psi, t, sub, 0, 1, G); } __syncthreads();
  { c4 G = mul4(cu4(mk3(tS, tC, tSh, tCh, 35)),                        // U26(3),U29(5);CU35(3->5)
                kron2(mk3(tS, tC, tSh, tCh, 26), mk3(tS, tC, tSh, tCh, 29)));
    g2q(psi, t, sub, 3, 5, G); } __syncthreads();
  { c4 G = gcxp(E(38)); g2q(psi, t, sub, 3, 1, G); } __syncthreads();  // CX(3,1);P38(1)
  { c4 G = mul4(kron2(mk3(tS, tC, tSh, tCh, 48), mk3(tS, tC, tSh, tCh, 51)),
                mul4(cu4(mk3(tS, tC, tSh, tCh, 45)),                   // U39,U42;CU45;U48,U51
                     kron2(mk3(tS, tC, tSh, tCh, 39), mk3(tS, tC, tSh, tCh, 42))));
    g2q(psi, t, sub, 0, 1, G); } __syncthreads();

  // A00 = <e0|U^H D U|e0> from column 0 (zero-norm fallback)
  if (tid < 64) {
    float2 v = psi[tid * 64];
    float term = (v.x * v.x + v.y * v.y) * (tid < 32 ? 1.f : -1.f);
#pragma unroll
    for (int m = 1; m < 64; m <<= 1) term += __shfl_xor(term, m, 64);
    if (tid == 0) g_A00 = term;
  }
  // P (128x64 bf16): rows [ReU i<32 | ImU i<32 | ReU i>=32 | ImU i>=32]
  for (int idx = tid; idx < 8192; idx += 256) {
    int r = idx >> 6, j = idx & 63;
    int i = (r < 32) ? r : (r < 96) ? (r - 32) : (r - 64);
    bool im = (r >= 32 && r < 64) || (r >= 96);
    float2 v = psi[i * 64 + j];
    g_P[idx] = f2bf(im ? v.y : v.x);
  }
}

#define MFMA(A, B, C) __builtin_amdgcn_mfma_f32_16x16x32_bf16(A, B, C, 0, 0, 0)

// ---- stream: no LDS, P fragments hoisted from global (L2 broadcast).
// out = (|Pp f|^2 - |Pm f|^2) / (|Pp f|^2 + |Pm f|^2); den free (U unitary).
// grid=1024 (4 blocks/CU, no LDS, no VGPR clamp): uniform 4 tiles/wave,
// branch-free fully-unrolled depth-2 pipeline. ----
__global__ __launch_bounds__(256) void qexp(const float* __restrict__ F,
                                            float* __restrict__ out) {
  const int tid = threadIdx.x;
  const int lane = tid & 63, wid = tid >> 6;
  const int g = lane >> 4, c0 = lane & 15;

  // A[m][k] = P[16*mt + m][k], m = lane&15, k = 8*(lane>>4)+i (+32*ks)
  const unsigned short* pb = g_P + c0 * 64 + g * 8;
  bf16x8 Bf[8][2];
#pragma unroll
  for (int mt = 0; mt < 8; ++mt) {
    Bf[mt][0] = *(const bf16x8*)(pb + mt * 1024);
    Bf[mt][1] = *(const bf16x8*)(pb + mt * 1024 + 32);
  }
  const float A00 = g_A00;

  // 4096 waves x 4 contiguous tiles (16384 tiles of 16 rows)
  const int gid   = (int)blockIdx.x * 4 + wid;
  const int start = gid * 4;
  // B[k][n] = F[row0 + n][k]: n = c0, k = 8*g + i (+32*ks)
  const float* fp = F + (size_t)start * 1024 + (size_t)c0 * 64 + g * 8;

#define LOADT(i, V0, V1, V2, V3) { const float* q_ = fp + (size_t)(i) * 1024; \
    V0 = *(const float4*)(q_); V1 = *(const float4*)(q_ + 4); \
    V2 = *(const float4*)(q_ + 32); V3 = *(const float4*)(q_ + 36); }

#define PROCESS(i, V0, V1, V2, V3) { \
    bf16x8 a0, a1; \
    a0[0] = f2bf(V0.x); a0[1] = f2bf(V0.y); a0[2] = f2bf(V0.z); a0[3] = f2bf(V0.w); \
    a0[4] = f2bf(V1.x); a0[5] = f2bf(V1.y); a0[6] = f2bf(V1.z); a0[7] = f2bf(V1.w); \
    a1[0] = f2bf(V2.x); a1[1] = f2bf(V2.y); a1[2] = f2bf(V2.z); a1[3] = f2bf(V2.w); \
    a1[4] = f2bf(V3.x); a1[5] = f2bf(V3.y); a1[6] = f2bf(V3.z); a1[7] = f2bf(V3.w); \
    f32x4 acc[8]; \
    _Pragma("unroll") \
    for (int mt = 0; mt < 8; ++mt) { \
      acc[mt] = (f32x4){0.f, 0.f, 0.f, 0.f}; \
      acc[mt] = MFMA(Bf[mt][0], a0, acc[mt]); \
      acc[mt] = MFMA(Bf[mt][1], a1, acc[mt]); \
    } \
    float sp_ = 0.f, sm_ = 0.f; \
    _Pragma("unroll") \
    for (int mt = 0; mt < 4; ++mt) { \
      _Pragma("unroll") \
      for (int r = 0; r < 4; ++r) { \
        sp_ = fmaf(acc[mt][r], acc[mt][r], sp_); \
        sm_ = fmaf(acc[mt + 4][r], acc[mt + 4][r], sm_); \
      } \
    } \
    sp_ += __shfl_xor(sp_, 16, 64); sm_ += __shfl_xor(sm_, 16, 64); \
    sp_ += __shfl_xor(sp_, 32, 64); sm_ += __shfl_xor(sm_, 32, 64); \
    if (lane < 16) { \
      float den = sp_ + sm_; \
      out[(size_t)(start + (i)) * 16 + c0] = (den < 1e-30f) ? A00 : (sp_ - sm_) / den; \
    } }

  float4 x0, x1, x2, x3, y0, y1, y2, y3;
  LOADT(0, x0, x1, x2, x3);
  LOADT(1, y0, y1, y2, y3);
  PROCESS(0, x0, x1, x2, x3);
  LOADT(2, x0, x1, x2, x3);
  PROCESS(1, y0, y1, y2, y3);
  LOADT(3, y0, y1, y2, y3);
  PROCESS(2, x0, x1, x2, x3);
  PROCESS(3, y0, y1, y2, y3);
#undef LOADT
#undef PROCESS
}

extern "C" void kernel_launch(void* const* d_in, const int* in_sizes, int n_in,
                              void* d_out, int out_size, void* d_ws, size_t ws_size,
                              hipStream_t stream) {
  const float* F = (const float*)d_in[0]; // (262144, 64) fp32
  const float* P = (const float*)d_in[1]; // (54,) fp32
  float* out = (float*)d_out;             // (262144,) fp32
  sim_kernel<<<1, 256, 0, stream>>>(P);
  qexp<<<1024, 256, 0, stream>>>(F, out);
}